// Round 2
// baseline (128.790 us; speedup 1.0000x reference)
//
#include <hip/hip_runtime.h>

#define NPTS 65536
#define NB_SHIFT 16   // log2(NPTS)
#define KNBR 16
#define HID 64

// native clang vector types — required by __builtin_nontemporal_{load,store}
typedef int   i32x4 __attribute__((ext_vector_type(4)));
typedef float f32x4 __attribute__((ext_vector_type(4)));

// ---------------- pre-pass: pos (B,3,N) -> xyzt (B,N) float4 ----------------
// Same XCD swizzle as the main kernel: XCD k writes exactly the table slice
// that its own main-kernel blocks will gather from -> local L2 dirty hits.
__global__ __launch_bounds__(256) void xyzt_kernel(const float* __restrict__ pos,
                                                   float4* __restrict__ xyzt) {
    const int tid = threadIdx.x;
    const int blk = ((int)blockIdx.x & 7) * 128 + ((int)blockIdx.x >> 3);
    const int g = blk * 256 + tid;
    const int b = g >> NB_SHIFT;
    const int n = g & (NPTS - 1);
    const float* p = pos + (size_t)b * 3 * NPTS;
    float4 v;
    v.x = __builtin_nontemporal_load(p + n);            // pos streamed once
    v.y = __builtin_nontemporal_load(p + n + NPTS);
    v.z = __builtin_nontemporal_load(p + n + 2 * NPTS);
    v.w = 0.f;
    // regular (caching) store: we WANT this resident in this XCD's L2
    xyzt[((size_t)b << NB_SHIFT) + n] = v;
}

// ---------------- main kernel ----------------
// USE_T = 1 : gather via transposed float4 table in ws
// USE_T = 0 : gather 3 scalars straight from pos (fallback, no ws needed)
template <int USE_T>
__global__ __launch_bounds__(256) void point_embed_kernel(
    const float*  __restrict__ pos,
    const float4* __restrict__ xyzt,
    const int*    __restrict__ idx,
    const float*  __restrict__ dist,
    const float*  __restrict__ W,
    const float*  __restrict__ bias,
    float*        __restrict__ out) {
    // SoA layout: phase-1 writes are lane-consecutive (conflict-free, vs 8-way
    // at the old stride-12 AoS); phase-2 reads are 16-lane broadcasts.
    __shared__ float feat[10][257];
    const int tid = threadIdx.x;

    // XCD-aware swizzle: 1024 blocks, 8 XCDs -> XCD k handles a contiguous
    // 128-block range => gather working set per XCD = 1 batch table (1 MB, L2-fit).
    const int blk = ((int)blockIdx.x & 7) * 128 + ((int)blockIdx.x >> 3);
    const int g = blk * 256 + tid;                    // global point id
    const int b = g >> NB_SHIFT;
    const int n = g & (NPTS - 1);

    // --- W slice for phase 2: this thread owns hidden cols 4*hq .. 4*hq+3 ---
    const int hq = tid & 15;
    float4 Wv[10];
#pragma unroll
    for (int c = 0; c < 10; ++c)
        Wv[c] = ((const float4*)(W + c * HID))[hq];   // tiny + reused: keep cached
    const float4 bv = ((const float4*)bias)[hq];

    // --- phase 1: per-point feature (10 floats) ---
    // idx/dist are streamed exactly once -> nontemporal, don't evict the
    // gather table from L2.
    const i32x4* iv = (const i32x4*)idx + (size_t)g * 4;
    i32x4 i0 = __builtin_nontemporal_load(iv + 0);
    i32x4 i1 = __builtin_nontemporal_load(iv + 1);
    i32x4 i2 = __builtin_nontemporal_load(iv + 2);
    i32x4 i3 = __builtin_nontemporal_load(iv + 3);
    const f32x4* dv = (const f32x4*)dist + (size_t)g * 4;
    f32x4 d0 = __builtin_nontemporal_load(dv + 0);
    f32x4 d1 = __builtin_nontemporal_load(dv + 1);
    f32x4 d2 = __builtin_nontemporal_load(dv + 2);
    f32x4 d3 = __builtin_nontemporal_load(dv + 3);
    float maxd = fmaxf(
        fmaxf(fmaxf(fmaxf(d0.x, d0.y), fmaxf(d0.z, d0.w)),
              fmaxf(fmaxf(d1.x, d1.y), fmaxf(d1.z, d1.w))),
        fmaxf(fmaxf(fmaxf(d2.x, d2.y), fmaxf(d2.z, d2.w)),
              fmaxf(fmaxf(d3.x, d3.y), fmaxf(d3.z, d3.w))));

    float cx, cy, cz;
    float mxx = -INFINITY, mxy = -INFINITY, mxz = -INFINITY;
    float mnx = INFINITY, mny = INFINITY, mnz = INFINITY;

    if (USE_T) {
        const float4* xb = xyzt + ((size_t)b << NB_SHIFT);
        float4 c = xb[n];
        cx = c.x; cy = c.y; cz = c.z;
#define GATH(J)                                   \
    {                                             \
        float4 q = xb[(J)];                       \
        mxx = fmaxf(mxx, q.x);                    \
        mxy = fmaxf(mxy, q.y);                    \
        mxz = fmaxf(mxz, q.z);                    \
        mnx = fminf(mnx, q.x);                    \
        mny = fminf(mny, q.y);                    \
        mnz = fminf(mnz, q.z);                    \
    }
        GATH(i0.x) GATH(i0.y) GATH(i0.z) GATH(i0.w)
        GATH(i1.x) GATH(i1.y) GATH(i1.z) GATH(i1.w)
        GATH(i2.x) GATH(i2.y) GATH(i2.z) GATH(i2.w)
        GATH(i3.x) GATH(i3.y) GATH(i3.z) GATH(i3.w)
#undef GATH
    } else {
        const float* px = pos + (size_t)b * 3 * NPTS;
        cx = px[n]; cy = px[n + NPTS]; cz = px[n + 2 * NPTS];
#define GATH(J)                                   \
    {                                             \
        float qx = px[(J)];                       \
        float qy = px[(J) + NPTS];                \
        float qz = px[(J) + 2 * NPTS];            \
        mxx = fmaxf(mxx, qx);                     \
        mxy = fmaxf(mxy, qy);                     \
        mxz = fmaxf(mxz, qz);                     \
        mnx = fminf(mnx, qx);                     \
        mny = fminf(mny, qy);                     \
        mnz = fminf(mnz, qz);                     \
    }
        GATH(i0.x) GATH(i0.y) GATH(i0.z) GATH(i0.w)
        GATH(i1.x) GATH(i1.y) GATH(i1.z) GATH(i1.w)
        GATH(i2.x) GATH(i2.y) GATH(i2.z) GATH(i2.w)
        GATH(i3.x) GATH(i3.y) GATH(i3.z) GATH(i3.w)
#undef GATH
    }

    feat[0][tid] = cx;
    feat[1][tid] = cy;
    feat[2][tid] = cz;
    feat[3][tid] = mxx;
    feat[4][tid] = mxy;
    feat[5][tid] = mxz;
    feat[6][tid] = cx - mnx;
    feat[7][tid] = cy - mny;
    feat[8][tid] = cz - mnz;
    feat[9][tid] = maxd;
    __syncthreads();

    // --- phase 2: 256 points x 64 hidden, coalesced nontemporal float4 stores ---
    const int prow = tid >> 4;                       // 0..15
    const size_t outbase = (size_t)blk * 256 * HID;
#pragma unroll
    for (int i = 0; i < 16; ++i) {
        const int p = i * 16 + prow;
        float4 acc = bv;
#pragma unroll
        for (int c = 0; c < 10; ++c) {
            const float fv = feat[c][p];
            acc.x += fv * Wv[c].x;
            acc.y += fv * Wv[c].y;
            acc.z += fv * Wv[c].z;
            acc.w += fv * Wv[c].w;
        }
        f32x4 av;
        av.x = fmaxf(acc.x, 0.f);
        av.y = fmaxf(acc.y, 0.f);
        av.z = fmaxf(acc.z, 0.f);
        av.w = fmaxf(acc.w, 0.f);
        // out is written once, never read back: don't write-allocate 67 MB in L2
        __builtin_nontemporal_store(av,
            (f32x4*)(out + outbase + (size_t)p * HID) + hq);
    }
}

extern "C" void kernel_launch(void* const* d_in, const int* in_sizes, int n_in,
                              void* d_out, int out_size, void* d_ws, size_t ws_size,
                              hipStream_t stream) {
    const float* pos  = (const float*)d_in[0];
    const int*   idx  = (const int*)d_in[1];
    const float* dist = (const float*)d_in[2];
    const float* W    = (const float*)d_in[3];
    const float* bias = (const float*)d_in[4];
    float* out = (float*)d_out;

    const int total   = in_sizes[0] / 3;     // B*N = 262144
    const int nblocks = total / 256;         // 1024
    const size_t need = (size_t)total * sizeof(float4);  // 16 MB

    if (ws_size >= need) {
        xyzt_kernel<<<nblocks, 256, 0, stream>>>(pos, (float4*)d_ws);
        point_embed_kernel<1><<<nblocks, 256, 0, stream>>>(
            pos, (const float4*)d_ws, idx, dist, W, bias, out);
    } else {
        point_embed_kernel<0><<<nblocks, 256, 0, stream>>>(
            pos, nullptr, idx, dist, W, bias, out);
    }
}

// Round 3
// 126.526 us; speedup vs baseline: 1.0179x; 1.0179x over previous
//
#include <hip/hip_runtime.h>

#define NPTS 65536
#define NB_SHIFT 16   // log2(NPTS)
#define KNBR 16
#define HID 64
#define PPB 128       // points per block in main kernel (2 threads per point)

// native clang vector types — required by __builtin_nontemporal_{load,store}
typedef int   i32x4 __attribute__((ext_vector_type(4)));
typedef float f32x4 __attribute__((ext_vector_type(4)));

// ---------------- pre-pass: pos (B,3,N) -> xyzt (B,N) float4 ----------------
// Same XCD swizzle family as the main kernel: XCD k writes the table slice
// its own main-kernel blocks gather from -> local L2 dirty hits.
__global__ __launch_bounds__(256) void xyzt_kernel(const float* __restrict__ pos,
                                                   float4* __restrict__ xyzt) {
    const int tid = threadIdx.x;
    const int blk = ((int)blockIdx.x & 7) * 128 + ((int)blockIdx.x >> 3);
    const int g = blk * 256 + tid;
    const int b = g >> NB_SHIFT;
    const int n = g & (NPTS - 1);
    const float* p = pos + (size_t)b * 3 * NPTS;
    float4 v;
    v.x = __builtin_nontemporal_load(p + n);            // pos streamed once
    v.y = __builtin_nontemporal_load(p + n + NPTS);
    v.z = __builtin_nontemporal_load(p + n + 2 * NPTS);
    v.w = 0.f;
    // regular (caching) store: we WANT this resident in this XCD's L2
    xyzt[((size_t)b << NB_SHIFT) + n] = v;
}

// ---------------- main kernel ----------------
// Pair-split: thread pair (2p, 2p+1) shares point p. Each half loads 8
// indices + 8 dists (one contiguous 32B chunk per thread -> coalesced),
// issues 8 gathers, then the pair merges via __shfl_xor(.,1).
// Grid = 2048 blocks -> 8 blocks/CU -> 32-wave/CU grid capacity (was 16).
template <int USE_T>
__global__ __launch_bounds__(256) void point_embed_kernel(
    const float*  __restrict__ pos,
    const float4* __restrict__ xyzt,
    const int*    __restrict__ idx,
    const float*  __restrict__ dist,
    const float*  __restrict__ W,
    const float*  __restrict__ bias,
    float*        __restrict__ out) {
    __shared__ float feat[10][PPB];
    const int tid = threadIdx.x;

    // XCD-aware swizzle: 2048 blocks, 8 XCDs -> XCD k gets a contiguous
    // 256-block range => gather working set per XCD = 1 batch table (1 MB).
    const int blk = ((int)blockIdx.x & 7) * 256 + ((int)blockIdx.x >> 3);
    const int p = tid >> 1;                           // 0..127 point-in-block
    const int h = tid & 1;                            // which half of K
    const int g = blk * PPB + p;                      // global point id
    const int b = g >> NB_SHIFT;
    const int n = g & (NPTS - 1);

    // --- W slice for phase 2: this thread owns hidden cols 4*hq .. 4*hq+3 ---
    const int hq = tid & 15;
    float4 Wv[10];
#pragma unroll
    for (int c = 0; c < 10; ++c)
        Wv[c] = ((const float4*)(W + c * HID))[hq];   // tiny + reused: keep cached
    const float4 bv = ((const float4*)bias)[hq];

    // --- phase 1: per-point feature (10 floats), split across the pair ---
    // idx/dist streamed exactly once -> nontemporal.
    const i32x4* iv = (const i32x4*)idx + (size_t)g * 4 + h * 2;
    i32x4 i0 = __builtin_nontemporal_load(iv + 0);
    i32x4 i1 = __builtin_nontemporal_load(iv + 1);
    const f32x4* dv = (const f32x4*)dist + (size_t)g * 4 + h * 2;
    f32x4 d0 = __builtin_nontemporal_load(dv + 0);
    f32x4 d1 = __builtin_nontemporal_load(dv + 1);
    float maxd = fmaxf(fmaxf(fmaxf(d0.x, d0.y), fmaxf(d0.z, d0.w)),
                       fmaxf(fmaxf(d1.x, d1.y), fmaxf(d1.z, d1.w)));

    float cx, cy, cz;
    float mxx = -INFINITY, mxy = -INFINITY, mxz = -INFINITY;
    float mnx = INFINITY, mny = INFINITY, mnz = INFINITY;

    if (USE_T) {
        const float4* xb = xyzt + ((size_t)b << NB_SHIFT);
        float4 c = xb[n];
        cx = c.x; cy = c.y; cz = c.z;
#define GATH(J)                                   \
    {                                             \
        float4 q = xb[(J)];                       \
        mxx = fmaxf(mxx, q.x);                    \
        mxy = fmaxf(mxy, q.y);                    \
        mxz = fmaxf(mxz, q.z);                    \
        mnx = fminf(mnx, q.x);                    \
        mny = fminf(mny, q.y);                    \
        mnz = fminf(mnz, q.z);                    \
    }
        GATH(i0.x) GATH(i0.y) GATH(i0.z) GATH(i0.w)
        GATH(i1.x) GATH(i1.y) GATH(i1.z) GATH(i1.w)
#undef GATH
    } else {
        const float* px = pos + (size_t)b * 3 * NPTS;
        cx = px[n]; cy = px[n + NPTS]; cz = px[n + 2 * NPTS];
#define GATH(J)                                   \
    {                                             \
        float qx = px[(J)];                       \
        float qy = px[(J) + NPTS];                \
        float qz = px[(J) + 2 * NPTS];            \
        mxx = fmaxf(mxx, qx);                     \
        mxy = fmaxf(mxy, qy);                     \
        mxz = fmaxf(mxz, qz);                     \
        mnx = fminf(mnx, qx);                     \
        mny = fminf(mny, qy);                     \
        mnz = fminf(mnz, qz);                     \
    }
        GATH(i0.x) GATH(i0.y) GATH(i0.z) GATH(i0.w)
        GATH(i1.x) GATH(i1.y) GATH(i1.z) GATH(i1.w)
#undef GATH
    }

    // --- merge the pair (lanes 2p and 2p+1 are in the same wave) ---
    mxx = fmaxf(mxx, __shfl_xor(mxx, 1));
    mxy = fmaxf(mxy, __shfl_xor(mxy, 1));
    mxz = fmaxf(mxz, __shfl_xor(mxz, 1));
    mnx = fminf(mnx, __shfl_xor(mnx, 1));
    mny = fminf(mny, __shfl_xor(mny, 1));
    mnz = fminf(mnz, __shfl_xor(mnz, 1));
    maxd = fmaxf(maxd, __shfl_xor(maxd, 1));

    if (h == 0) {
        feat[0][p] = cx;
        feat[1][p] = cy;
        feat[2][p] = cz;
        feat[3][p] = mxx;
        feat[4][p] = mxy;
        feat[5][p] = mxz;
        feat[6][p] = cx - mnx;
        feat[7][p] = cy - mny;
        feat[8][p] = cz - mnz;
        feat[9][p] = maxd;
    }
    __syncthreads();

    // --- phase 2: 128 points x 64 hidden, coalesced nontemporal float4 stores ---
    const int prow = tid >> 4;                       // 0..15
    const size_t outbase = (size_t)blk * PPB * HID;
#pragma unroll
    for (int i = 0; i < 8; ++i) {
        const int pp = i * 16 + prow;                // 0..127
        float4 acc = bv;
#pragma unroll
        for (int c = 0; c < 10; ++c) {
            const float fv = feat[c][pp];
            acc.x += fv * Wv[c].x;
            acc.y += fv * Wv[c].y;
            acc.z += fv * Wv[c].z;
            acc.w += fv * Wv[c].w;
        }
        f32x4 av;
        av.x = fmaxf(acc.x, 0.f);
        av.y = fmaxf(acc.y, 0.f);
        av.z = fmaxf(acc.z, 0.f);
        av.w = fmaxf(acc.w, 0.f);
        // out written once, never read back: don't write-allocate 67 MB in L2
        __builtin_nontemporal_store(av,
            (f32x4*)(out + outbase + (size_t)pp * HID) + hq);
    }
}

extern "C" void kernel_launch(void* const* d_in, const int* in_sizes, int n_in,
                              void* d_out, int out_size, void* d_ws, size_t ws_size,
                              hipStream_t stream) {
    const float* pos  = (const float*)d_in[0];
    const int*   idx  = (const int*)d_in[1];
    const float* dist = (const float*)d_in[2];
    const float* W    = (const float*)d_in[3];
    const float* bias = (const float*)d_in[4];
    float* out = (float*)d_out;

    const int total = in_sizes[0] / 3;       // B*N = 262144
    const size_t need = (size_t)total * sizeof(float4);  // 16 MB

    if (ws_size >= need) {
        xyzt_kernel<<<total / 256, 256, 0, stream>>>(pos, (float4*)d_ws);
        point_embed_kernel<1><<<total / PPB, 256, 0, stream>>>(
            pos, (const float4*)d_ws, idx, dist, W, bias, out);
    } else {
        point_embed_kernel<0><<<total / PPB, 256, 0, stream>>>(
            pos, nullptr, idx, dist, W, bias, out);
    }
}

// Round 4
// 125.285 us; speedup vs baseline: 1.0280x; 1.0099x over previous
//
#include <hip/hip_runtime.h>

#define NPTS 65536
#define NB_SHIFT 16   // log2(NPTS)
#define KNBR 16
#define HID 64
#define PPB 128       // points per block in main kernel (2 threads per point)

// native clang vector types — required by __builtin_nontemporal_{load,store}
typedef int   i32x4 __attribute__((ext_vector_type(4)));
typedef float f32x4 __attribute__((ext_vector_type(4)));

// ---------------- pre-pass: pos (B,3,N) -> xyzt (B,N) float4 ----------------
__global__ __launch_bounds__(256) void xyzt_kernel(const float* __restrict__ pos,
                                                   float4* __restrict__ xyzt) {
    const int tid = threadIdx.x;
    const int blk = ((int)blockIdx.x & 7) * 128 + ((int)blockIdx.x >> 3);
    const int g = blk * 256 + tid;
    const int b = g >> NB_SHIFT;
    const int n = g & (NPTS - 1);
    const float* p = pos + (size_t)b * 3 * NPTS;
    float4 v;
    v.x = __builtin_nontemporal_load(p + n);            // pos streamed once
    v.y = __builtin_nontemporal_load(p + n + NPTS);
    v.z = __builtin_nontemporal_load(p + n + 2 * NPTS);
    v.w = 0.f;
    // caching store: we WANT this resident in L2 for the gather kernel
    xyzt[((size_t)b << NB_SHIFT) + n] = v;
}

// ---------------- main kernel ----------------
// Pair-split (2 threads/point). Gathers use inline-asm global_load_dwordx4
// with sc0: L1-bypass, no 128B line fill for lines that have ~0 reuse at
// block scope. Table (4 MB total) is L2-resident; sc0 loads are L2 hits.
template <int USE_T>
__global__ __launch_bounds__(256) void point_embed_kernel(
    const float*  __restrict__ pos,
    const float4* __restrict__ xyzt,
    const int*    __restrict__ idx,
    const float*  __restrict__ dist,
    const float*  __restrict__ W,
    const float*  __restrict__ bias,
    float*        __restrict__ out) {
    __shared__ float feat[10][PPB];
    const int tid = threadIdx.x;

    // XCD-aware swizzle: contiguous block ranges per XCD -> per-XCD gather
    // working set stays small and L2-resident.
    const int blk = ((int)blockIdx.x & 7) * 256 + ((int)blockIdx.x >> 3);
    const int p = tid >> 1;                           // 0..127 point-in-block
    const int h = tid & 1;                            // which half of K
    const int g = blk * PPB + p;                      // global point id
    const int b = g >> NB_SHIFT;
    const int n = g & (NPTS - 1);

    // --- W slice for phase 2: this thread owns hidden cols 4*hq .. 4*hq+3 ---
    const int hq = tid & 15;
    float4 Wv[10];
#pragma unroll
    for (int c = 0; c < 10; ++c)
        Wv[c] = ((const float4*)(W + c * HID))[hq];
    const float4 bv = ((const float4*)bias)[hq];

    // --- phase 1: per-point feature (10 floats), split across the pair ---
    const i32x4* iv = (const i32x4*)idx + (size_t)g * 4 + h * 2;
    i32x4 i0 = __builtin_nontemporal_load(iv + 0);
    i32x4 i1 = __builtin_nontemporal_load(iv + 1);
    const f32x4* dv = (const f32x4*)dist + (size_t)g * 4 + h * 2;
    f32x4 d0 = __builtin_nontemporal_load(dv + 0);
    f32x4 d1 = __builtin_nontemporal_load(dv + 1);
    float maxd = fmaxf(fmaxf(fmaxf(d0.x, d0.y), fmaxf(d0.z, d0.w)),
                       fmaxf(fmaxf(d1.x, d1.y), fmaxf(d1.z, d1.w)));

    float cx, cy, cz;
    float mxx = -INFINITY, mxy = -INFINITY, mxz = -INFINITY;
    float mnx = INFINITY, mny = INFINITY, mnz = INFINITY;

    if (USE_T) {
        const f32x4* xb = (const f32x4*)(xyzt + ((size_t)b << NB_SHIFT));
        // center load: coalesced across the wave -> keep the cached path
        float4 c = xyzt[((size_t)b << NB_SHIFT) + n];
        cx = c.x; cy = c.y; cz = c.z;

        // 8 L1-bypass gathers (sc0): issue all, single drain, fenced consume.
        f32x4 q0, q1, q2, q3, q4, q5, q6, q7;
        const f32x4* a0 = xb + i0.x;
        const f32x4* a1 = xb + i0.y;
        const f32x4* a2 = xb + i0.z;
        const f32x4* a3 = xb + i0.w;
        const f32x4* a4 = xb + i1.x;
        const f32x4* a5 = xb + i1.y;
        const f32x4* a6 = xb + i1.z;
        const f32x4* a7 = xb + i1.w;
        asm volatile("global_load_dwordx4 %0, %1, off sc0" : "=v"(q0) : "v"(a0));
        asm volatile("global_load_dwordx4 %0, %1, off sc0" : "=v"(q1) : "v"(a1));
        asm volatile("global_load_dwordx4 %0, %1, off sc0" : "=v"(q2) : "v"(a2));
        asm volatile("global_load_dwordx4 %0, %1, off sc0" : "=v"(q3) : "v"(a3));
        asm volatile("global_load_dwordx4 %0, %1, off sc0" : "=v"(q4) : "v"(a4));
        asm volatile("global_load_dwordx4 %0, %1, off sc0" : "=v"(q5) : "v"(a5));
        asm volatile("global_load_dwordx4 %0, %1, off sc0" : "=v"(q6) : "v"(a6));
        asm volatile("global_load_dwordx4 %0, %1, off sc0" : "=v"(q7) : "v"(a7));
        asm volatile("s_waitcnt vmcnt(0)" ::: "memory");
        __builtin_amdgcn_sched_barrier(0);   // rule-18: keep consumers below the wait

#define RED(Q)                                    \
    {                                             \
        mxx = fmaxf(mxx, (Q).x);                  \
        mxy = fmaxf(mxy, (Q).y);                  \
        mxz = fmaxf(mxz, (Q).z);                  \
        mnx = fminf(mnx, (Q).x);                  \
        mny = fminf(mny, (Q).y);                  \
        mnz = fminf(mnz, (Q).z);                  \
    }
        RED(q0) RED(q1) RED(q2) RED(q3) RED(q4) RED(q5) RED(q6) RED(q7)
#undef RED
    } else {
        const float* px = pos + (size_t)b * 3 * NPTS;
        cx = px[n]; cy = px[n + NPTS]; cz = px[n + 2 * NPTS];
#define GATH(J)                                   \
    {                                             \
        float qx = px[(J)];                       \
        float qy = px[(J) + NPTS];                \
        float qz = px[(J) + 2 * NPTS];            \
        mxx = fmaxf(mxx, qx);                     \
        mxy = fmaxf(mxy, qy);                     \
        mxz = fmaxf(mxz, qz);                     \
        mnx = fminf(mnx, qx);                     \
        mny = fminf(mny, qy);                     \
        mnz = fminf(mnz, qz);                     \
    }
        GATH(i0.x) GATH(i0.y) GATH(i0.z) GATH(i0.w)
        GATH(i1.x) GATH(i1.y) GATH(i1.z) GATH(i1.w)
#undef GATH
    }

    // --- merge the pair (lanes 2p and 2p+1 are in the same wave) ---
    mxx = fmaxf(mxx, __shfl_xor(mxx, 1));
    mxy = fmaxf(mxy, __shfl_xor(mxy, 1));
    mxz = fmaxf(mxz, __shfl_xor(mxz, 1));
    mnx = fminf(mnx, __shfl_xor(mnx, 1));
    mny = fminf(mny, __shfl_xor(mny, 1));
    mnz = fminf(mnz, __shfl_xor(mnz, 1));
    maxd = fmaxf(maxd, __shfl_xor(maxd, 1));

    if (h == 0) {
        feat[0][p] = cx;
        feat[1][p] = cy;
        feat[2][p] = cz;
        feat[3][p] = mxx;
        feat[4][p] = mxy;
        feat[5][p] = mxz;
        feat[6][p] = cx - mnx;
        feat[7][p] = cy - mny;
        feat[8][p] = cz - mnz;
        feat[9][p] = maxd;
    }
    __syncthreads();

    // --- phase 2: 128 points x 64 hidden, coalesced nontemporal float4 stores ---
    const int prow = tid >> 4;                       // 0..15
    const size_t outbase = (size_t)blk * PPB * HID;
#pragma unroll
    for (int i = 0; i < 8; ++i) {
        const int pp = i * 16 + prow;                // 0..127
        float4 acc = bv;
#pragma unroll
        for (int c = 0; c < 10; ++c) {
            const float fv = feat[c][pp];
            acc.x += fv * Wv[c].x;
            acc.y += fv * Wv[c].y;
            acc.z += fv * Wv[c].z;
            acc.w += fv * Wv[c].w;
        }
        f32x4 av;
        av.x = fmaxf(acc.x, 0.f);
        av.y = fmaxf(acc.y, 0.f);
        av.z = fmaxf(acc.z, 0.f);
        av.w = fmaxf(acc.w, 0.f);
        // out written once, never read back: don't write-allocate 67 MB in L2
        __builtin_nontemporal_store(av,
            (f32x4*)(out + outbase + (size_t)pp * HID) + hq);
    }
}

extern "C" void kernel_launch(void* const* d_in, const int* in_sizes, int n_in,
                              void* d_out, int out_size, void* d_ws, size_t ws_size,
                              hipStream_t stream) {
    const float* pos  = (const float*)d_in[0];
    const int*   idx  = (const int*)d_in[1];
    const float* dist = (const float*)d_in[2];
    const float* W    = (const float*)d_in[3];
    const float* bias = (const float*)d_in[4];
    float* out = (float*)d_out;

    const int total = in_sizes[0] / 3;       // B*N = 262144
    const size_t need = (size_t)total * sizeof(float4);  // 16 MB

    if (ws_size >= need) {
        xyzt_kernel<<<total / 256, 256, 0, stream>>>(pos, (float4*)d_ws);
        point_embed_kernel<1><<<total / PPB, 256, 0, stream>>>(
            pos, (const float4*)d_ws, idx, dist, W, bias, out);
    } else {
        point_embed_kernel<0><<<total / PPB, 256, 0, stream>>>(
            pos, nullptr, idx, dist, W, bias, out);
    }
}